// Round 1
// baseline (349.117 us; speedup 1.0000x reference)
//
#include <hip/hip_runtime.h>
#include <hip/hip_bf16.h>
#include <stdint.h>

#define BATCH 8
#define NN 4096
#define DD 64
#define CC 512

using f32x4  = __attribute__((ext_vector_type(4))) float;
using bf16x8 = __attribute__((ext_vector_type(8))) short;

__device__ __forceinline__ uint16_t f2bf(float f) {
  union { float f; uint32_t u; } v; v.f = f;
  uint32_t r = v.u + 0x7fffu + ((v.u >> 16) & 1u);
  return (uint16_t)(r >> 16);
}

// ---------------- Wv -> bf16 ----------------
__global__ void cvt_wv_kernel(const float* __restrict__ Wv, uint16_t* __restrict__ Wvb) {
  int i = blockIdx.x * 256 + threadIdx.x;
  if (i < CC * DD) Wvb[i] = f2bf(Wv[i]);
}

// ---------------- projections: ff/fg/fh ----------------
// grid (NN/64, BATCH, 3), block 256.  p=0 -> Q(ff), p=1 -> K(fg), p=2 -> Vt(fh^T)
__global__ void proj_kernel(const float* __restrict__ x,
                            const float* __restrict__ Wf, const float* __restrict__ bfp,
                            const float* __restrict__ Wg, const float* __restrict__ bgp,
                            const float* __restrict__ Wh, const float* __restrict__ bhp,
                            uint16_t* __restrict__ Qb, uint16_t* __restrict__ Kb,
                            uint16_t* __restrict__ Vt) {
  const int nt = blockIdx.x;
  const int b  = blockIdx.y;
  const int p  = blockIdx.z;

  const float* W    = (p == 0) ? Wf  : (p == 1) ? Wg  : Wh;
  const float* bias = (p == 0) ? bfp : (p == 1) ? bgp : bhp;

  __shared__ float xl[32][68];   // [k][n]  pad->bank stride 4
  __shared__ float wl[32][68];   // [k][ch]

  const int t  = threadIdx.x;
  const int tn = t & 15;         // 4 n rows each
  const int tc = t >> 4;         // 4 ch cols each
  const int n0 = nt * 64;

  const float* xp = x + (size_t)b * CC * NN + n0;

  float acc[4][4] = {};

  for (int k0 = 0; k0 < CC; k0 += 32) {
#pragma unroll
    for (int j = 0; j < 8; ++j) {           // 32x64 x-tile, coalesced along n
      int idx = t + j * 256;
      xl[idx >> 6][idx & 63] = xp[(size_t)(k0 + (idx >> 6)) * NN + (idx & 63)];
    }
#pragma unroll
    for (int j = 0; j < 8; ++j) {           // 64ch x 32c W-tile, transposed store
      int idx = t + j * 256;
      wl[idx & 31][idx >> 5] = W[(size_t)(idx >> 5) * CC + k0 + (idx & 31)];
    }
    __syncthreads();
#pragma unroll
    for (int k = 0; k < 32; ++k) {
      f32x4 xv = *(const f32x4*)&xl[k][tn * 4];
      f32x4 wv = *(const f32x4*)&wl[k][tc * 4];
#pragma unroll
      for (int i = 0; i < 4; ++i)
#pragma unroll
        for (int j = 0; j < 4; ++j)
          acc[i][j] = fmaf(xv[i], wv[j], acc[i][j]);
    }
    __syncthreads();
  }

  const int ch0 = tc * 4;
  float bvals[4];
#pragma unroll
  for (int j = 0; j < 4; ++j) bvals[j] = bias[ch0 + j];

  if (p < 2) {
    // Q/K layout: [b][n][64] bf16
    uint16_t* dst = (p == 0 ? Qb : Kb) + ((size_t)b * NN + n0) * DD;
#pragma unroll
    for (int i = 0; i < 4; ++i) {
      uint16_t v[4];
#pragma unroll
      for (int j = 0; j < 4; ++j) v[j] = f2bf(acc[i][j] + bvals[j]);
      *(uint2*)&dst[(size_t)(tn * 4 + i) * DD + ch0] = *(const uint2*)v;
    }
  } else {
    // Vt layout: [b][64][n] bf16 (transposed)
    uint16_t* dst = Vt + (size_t)b * DD * NN + n0;
#pragma unroll
    for (int j = 0; j < 4; ++j) {
      uint16_t v[4];
#pragma unroll
      for (int i = 0; i < 4; ++i) v[i] = f2bf(acc[i][j] + bvals[j]);
      *(uint2*)&dst[(size_t)(ch0 + j) * NN + tn * 4] = *(const uint2*)v;
    }
  }
}

// ---------------- fused flash attention + O@Wv^T + residual ----------------
// grid (NN/64, BATCH), block 256 = 4 independent waves, 16 q-rows each.
__global__ __launch_bounds__(256) void flash_kernel(
    const uint16_t* __restrict__ Qb, const uint16_t* __restrict__ Kb,
    const uint16_t* __restrict__ Vt, const uint16_t* __restrict__ Wvb,
    const float* __restrict__ bv, const float* __restrict__ x,
    const float* __restrict__ sigma, float* __restrict__ out) {
  const int qt = blockIdx.x;
  const int b  = blockIdx.y;
  const int t    = threadIdx.x;
  const int wave = t >> 6;
  const int lane = t & 63;
  const int lg   = lane >> 4;   // k-chunk group
  const int lm   = lane & 15;   // m/n index

  __shared__ uint16_t plds[4][16][72];   // per-wave P/O staging, 72 = 64 + 8 pad
  uint16_t (*pl)[72] = plds[wave];

  const int q0 = qt * 64 + wave * 16;

  // Q A-fragments (held for whole kernel): Q[q0+lm][lg*8 + j (+32)]
  const uint16_t* Qp = Qb + ((size_t)b * NN + q0 + lm) * DD + lg * 8;
  bf16x8 qa0 = *(const bf16x8*)Qp;
  bf16x8 qa1 = *(const bf16x8*)(Qp + 32);

  const uint16_t* Kbase = Kb + (size_t)b * NN * DD;
  const uint16_t* Vbase = Vt + (size_t)b * DD * NN;

  f32x4 o[4] = {};               // O[q 16][d 64]: o[td][reg]
  float m[4], l[4];
#pragma unroll
  for (int r = 0; r < 4; ++r) { m[r] = -1e30f; l[r] = 0.f; }

  for (int kv0 = 0; kv0 < NN; kv0 += 64) {
    // ---- S = Q K^T for 16q x 64kv ----
    f32x4 s[4];
#pragma unroll
    for (int tk = 0; tk < 4; ++tk) s[tk] = (f32x4){0.f, 0.f, 0.f, 0.f};
#pragma unroll
    for (int tk = 0; tk < 4; ++tk) {
      const uint16_t* Kp = Kbase + (size_t)(kv0 + tk * 16 + lm) * DD + lg * 8;
      bf16x8 kb0 = *(const bf16x8*)Kp;
      bf16x8 kb1 = *(const bf16x8*)(Kp + 32);
      s[tk] = __builtin_amdgcn_mfma_f32_16x16x32_bf16(qa0, kb0, s[tk], 0, 0, 0);
      s[tk] = __builtin_amdgcn_mfma_f32_16x16x32_bf16(qa1, kb1, s[tk], 0, 0, 0);
    }

    // ---- online softmax (rows live in 16-lane groups; reduce over lm) ----
    float pmax[4], mn[4], sc[4], rs[4];
#pragma unroll
    for (int r = 0; r < 4; ++r)
      pmax[r] = fmaxf(fmaxf(s[0][r], s[1][r]), fmaxf(s[2][r], s[3][r]));
#pragma unroll
    for (int d = 1; d < 16; d <<= 1)
#pragma unroll
      for (int r = 0; r < 4; ++r)
        pmax[r] = fmaxf(pmax[r], __shfl_xor(pmax[r], d, 64));
#pragma unroll
    for (int r = 0; r < 4; ++r) {
      mn[r] = fmaxf(m[r], pmax[r]);
      sc[r] = __expf(m[r] - mn[r]);
      m[r]  = mn[r];
      rs[r] = 0.f;
    }
#pragma unroll
    for (int tk = 0; tk < 4; ++tk)
#pragma unroll
      for (int r = 0; r < 4; ++r) {
        float e = __expf(s[tk][r] - mn[r]);
        s[tk][r] = e;
        rs[r] += e;
      }
#pragma unroll
    for (int d = 1; d < 16; d <<= 1)
#pragma unroll
      for (int r = 0; r < 4; ++r)
        rs[r] += __shfl_xor(rs[r], d, 64);
#pragma unroll
    for (int r = 0; r < 4; ++r) l[r] = l[r] * sc[r] + rs[r];
#pragma unroll
    for (int td = 0; td < 4; ++td)
#pragma unroll
      for (int r = 0; r < 4; ++r) o[td][r] *= sc[r];

    // ---- P -> LDS (bf16, exact D-layout knowledge) ----
#pragma unroll
    for (int tk = 0; tk < 4; ++tk)
#pragma unroll
      for (int r = 0; r < 4; ++r)
        pl[lg * 4 + r][tk * 16 + lm] = f2bf(s[tk][r]);
    __threadfence_block();   // order LDS writes before cross-lane reads (same wave)

    // ---- O += P V ----
    bf16x8 pa0 = *(const bf16x8*)&pl[lm][lg * 8];
    bf16x8 pa1 = *(const bf16x8*)&pl[lm][32 + lg * 8];
#pragma unroll
    for (int td = 0; td < 4; ++td) {
      const uint16_t* Vp = Vbase + (size_t)(td * 16 + lm) * NN + kv0 + lg * 8;
      bf16x8 vb0 = *(const bf16x8*)Vp;
      bf16x8 vb1 = *(const bf16x8*)(Vp + 32);
      o[td] = __builtin_amdgcn_mfma_f32_16x16x32_bf16(pa0, vb0, o[td], 0, 0, 0);
      o[td] = __builtin_amdgcn_mfma_f32_16x16x32_bf16(pa1, vb1, o[td], 0, 0, 0);
    }
  }

  // ---- normalize, stage O, fused epilogue: out = x + sigma*(O Wv^T + bv) ----
  float inv[4];
#pragma unroll
  for (int r = 0; r < 4; ++r) inv[r] = 1.0f / l[r];
#pragma unroll
  for (int td = 0; td < 4; ++td)
#pragma unroll
    for (int r = 0; r < 4; ++r)
      pl[lg * 4 + r][td * 16 + lm] = f2bf(o[td][r] * inv[r]);
  __threadfence_block();

  bf16x8 oa0 = *(const bf16x8*)&pl[lm][lg * 8];
  bf16x8 oa1 = *(const bf16x8*)&pl[lm][32 + lg * 8];

  const float sg = sigma[0];
  const float* xb = x   + (size_t)b * CC * NN;
  float*       ob = out + (size_t)b * CC * NN;
  const int qr = q0 + lg * 4;

#pragma unroll 4
  for (int tc2 = 0; tc2 < 32; ++tc2) {
    const int c = tc2 * 16 + lm;
    const uint16_t* Wp = Wvb + (size_t)c * DD + lg * 8;
    bf16x8 wb0 = *(const bf16x8*)Wp;
    bf16x8 wb1 = *(const bf16x8*)(Wp + 32);
    f32x4 a = (f32x4){0.f, 0.f, 0.f, 0.f};
    a = __builtin_amdgcn_mfma_f32_16x16x32_bf16(oa0, wb0, a, 0, 0, 0);
    a = __builtin_amdgcn_mfma_f32_16x16x32_bf16(oa1, wb1, a, 0, 0, 0);
    const float bvc = bv[c];
    size_t base = (size_t)c * NN + qr;
    f32x4 xv = *(const f32x4*)(xb + base);
    f32x4 ov;
#pragma unroll
    for (int r = 0; r < 4; ++r) ov[r] = xv[r] + sg * (a[r] + bvc);
    *(f32x4*)(ob + base) = ov;
  }
}

extern "C" void kernel_launch(void* const* d_in, const int* in_sizes, int n_in,
                              void* d_out, int out_size, void* d_ws, size_t ws_size,
                              hipStream_t stream) {
  const float* x   = (const float*)d_in[0];
  const float* Wf  = (const float*)d_in[1];
  const float* bfp = (const float*)d_in[2];
  const float* Wg  = (const float*)d_in[3];
  const float* bgp = (const float*)d_in[4];
  const float* Wh  = (const float*)d_in[5];
  const float* bhp = (const float*)d_in[6];
  const float* Wv  = (const float*)d_in[7];
  const float* bv  = (const float*)d_in[8];
  const float* sg  = (const float*)d_in[9];
  float* out = (float*)d_out;

  uint16_t* Qb  = (uint16_t*)d_ws;
  uint16_t* Kb  = Qb + (size_t)BATCH * NN * DD;
  uint16_t* Vt  = Kb + (size_t)BATCH * NN * DD;
  uint16_t* Wvb = Vt + (size_t)BATCH * NN * DD;   // + 64 KB; total ~12.6 MB of ws

  hipLaunchKernelGGL(cvt_wv_kernel, dim3(CC * DD / 256), dim3(256), 0, stream, Wv, Wvb);
  hipLaunchKernelGGL(proj_kernel, dim3(NN / 64, BATCH, 3), dim3(256), 0, stream,
                     x, Wf, bfp, Wg, bgp, Wh, bhp, Qb, Kb, Vt);
  hipLaunchKernelGGL(flash_kernel, dim3(NN / 64, BATCH), dim3(256), 0, stream,
                     Qb, Kb, Vt, Wvb, bv, x, sg, out);
}

// Round 2
// 215.889 us; speedup vs baseline: 1.6171x; 1.6171x over previous
//
#include <hip/hip_runtime.h>
#include <hip/hip_bf16.h>
#include <stdint.h>

#define BATCH 8
#define NN 4096
#define DD 64
#define CC 512
#define SPLIT 2
#define NT (NN / SPLIT / 64)   // 32 kv-tiles per split

using f32x4  = __attribute__((ext_vector_type(4))) float;
using bf16x8 = __attribute__((ext_vector_type(8))) short;

__device__ __forceinline__ uint16_t f2bf(float f) {
  union { float f; uint32_t u; } v; v.f = f;
  uint32_t r = v.u + 0x7fffu + ((v.u >> 16) & 1u);
  return (uint16_t)(r >> 16);
}

__device__ __forceinline__ void gload16(const void* g, void* l) {
  __builtin_amdgcn_global_load_lds((const __attribute__((address_space(1))) void*)g,
                                   (__attribute__((address_space(3))) void*)l, 16, 0, 0);
}

// ---------------- Wv -> bf16 ----------------
__global__ void cvt_wv_kernel(const float* __restrict__ Wv, uint16_t* __restrict__ Wvb) {
  int i = blockIdx.x * 256 + threadIdx.x;
  if (i < CC * DD) Wvb[i] = f2bf(Wv[i]);
}

// ---------------- projections: ff/fg/fh (unchanged fp32 VALU GEMM) ----------------
__global__ void proj_kernel(const float* __restrict__ x,
                            const float* __restrict__ Wf, const float* __restrict__ bfp,
                            const float* __restrict__ Wg, const float* __restrict__ bgp,
                            const float* __restrict__ Wh, const float* __restrict__ bhp,
                            uint16_t* __restrict__ Qb, uint16_t* __restrict__ Kb,
                            uint16_t* __restrict__ Vt) {
  const int nt = blockIdx.x;
  const int b  = blockIdx.y;
  const int p  = blockIdx.z;

  const float* W    = (p == 0) ? Wf  : (p == 1) ? Wg  : Wh;
  const float* bias = (p == 0) ? bfp : (p == 1) ? bgp : bhp;

  __shared__ float xl[32][68];
  __shared__ float wl[32][68];

  const int t  = threadIdx.x;
  const int tn = t & 15;
  const int tc = t >> 4;
  const int n0 = nt * 64;

  const float* xp = x + (size_t)b * CC * NN + n0;

  float acc[4][4] = {};

  for (int k0 = 0; k0 < CC; k0 += 32) {
#pragma unroll
    for (int j = 0; j < 8; ++j) {
      int idx = t + j * 256;
      xl[idx >> 6][idx & 63] = xp[(size_t)(k0 + (idx >> 6)) * NN + (idx & 63)];
    }
#pragma unroll
    for (int j = 0; j < 8; ++j) {
      int idx = t + j * 256;
      wl[idx & 31][idx >> 5] = W[(size_t)(idx >> 5) * CC + k0 + (idx & 31)];
    }
    __syncthreads();
#pragma unroll
    for (int k = 0; k < 32; ++k) {
      f32x4 xv = *(const f32x4*)&xl[k][tn * 4];
      f32x4 wv = *(const f32x4*)&wl[k][tc * 4];
#pragma unroll
      for (int i = 0; i < 4; ++i)
#pragma unroll
        for (int j = 0; j < 4; ++j)
          acc[i][j] = fmaf(xv[i], wv[j], acc[i][j]);
    }
    __syncthreads();
  }

  const int ch0 = tc * 4;
  float bvals[4];
#pragma unroll
  for (int j = 0; j < 4; ++j) bvals[j] = bias[ch0 + j];

  if (p < 2) {
    uint16_t* dst = (p == 0 ? Qb : Kb) + ((size_t)b * NN + n0) * DD;
#pragma unroll
    for (int i = 0; i < 4; ++i) {
      uint16_t v[4];
#pragma unroll
      for (int j = 0; j < 4; ++j) v[j] = f2bf(acc[i][j] + bvals[j]);
      *(uint2*)&dst[(size_t)(tn * 4 + i) * DD + ch0] = *(const uint2*)v;
    }
  } else {
    uint16_t* dst = Vt + (size_t)b * DD * NN + n0;
#pragma unroll
    for (int j = 0; j < 4; ++j) {
      uint16_t v[4];
#pragma unroll
      for (int i = 0; i < 4; ++i) v[i] = f2bf(acc[i][j] + bvals[j]);
      *(uint2*)&dst[(size_t)(ch0 + j) * NN + tn * 4] = *(const uint2*)v;
    }
  }
}

// ---------------- flash attention partial (split-KV) ----------------
// grid (NN/64, BATCH, SPLIT), block 256 = 4 waves x 16 q-rows.
// K,V tiles LDS-staged (global_load_lds w16, src-side XOR swizzle), double-buffered.
// Swapped QK^T: s = mfma(K,Q) -> lane(lm,lg) holds S[q=lm][kv=16tk+4lg+r].
__global__ __launch_bounds__(256) void flash_kernel(
    const uint16_t* __restrict__ Qb, const uint16_t* __restrict__ Kb,
    const uint16_t* __restrict__ Vt,
    float* __restrict__ mpart, float* __restrict__ lpart, float* __restrict__ opart) {
  const int qt = blockIdx.x;
  const int b  = blockIdx.y;
  const int z  = blockIdx.z;
  const int t    = threadIdx.x;
  const int wave = t >> 6;
  const int lane = t & 63;
  const int lg   = lane >> 4;
  const int lm   = lane & 15;

  __shared__ uint16_t kv_lds[2][2][64 * 64];   // [buf][K/V][row*64+col] 32 KB
  __shared__ uint16_t plds[4][16][72];         // per-wave P staging
  uint16_t (*plw)[72] = plds[wave];

  const int q0 = qt * 64 + wave * 16;
  const uint16_t* Qp = Qb + ((size_t)b * NN + q0 + lm) * DD + lg * 8;
  bf16x8 qa0 = *(const bf16x8*)Qp;
  bf16x8 qa1 = *(const bf16x8*)(Qp + 32);

  const uint16_t* Kbase = Kb + (size_t)b * NN * DD;   // [n][64]
  const uint16_t* Vbase = Vt + (size_t)b * DD * NN;   // [d][4096]
  const int kvstart = z * (NN / SPLIT);

  // staging geometry: per wave 2KB K + 2KB V, 2 insts each.
  // LDS linear off (within region) = wave*2048 + i*1024 + lane*16 bytes
  // row = wave*16 + i*8 + (lane>>3), chunk c = lane&7, src chunk = c ^ (row&7)
  const int srow = wave * 16 + (lane >> 3);
  const int csw  = (lane & 7) ^ ((lane >> 3) & 7);

  auto stage = [&](int buf, int kv0) {
    uint16_t* kl = &kv_lds[buf][0][0] + wave * 1024;
    uint16_t* vl = &kv_lds[buf][1][0] + wave * 1024;
    gload16(Kbase + ((size_t)kv0 + srow) * DD + csw * 8,       kl);
    gload16(Kbase + ((size_t)kv0 + srow + 8) * DD + csw * 8,   kl + 512);
    gload16(Vbase + (size_t)srow * NN + kv0 + csw * 8,         vl);
    gload16(Vbase + (size_t)(srow + 8) * NN + kv0 + csw * 8,   vl + 512);
  };

  f32x4 o[4] = {};
  float m = -1e30f, l = 0.f;

  stage(0, kvstart);
  __syncthreads();

  int cur = 0;
  const int sw = lm & 7;
  for (int it = 0; it < NT; ++it) {
    const int kv0 = kvstart + it * 64;
    if (it + 1 < NT) stage(cur ^ 1, kv0 + 64);   // async prefetch, lands by the end-of-iter sync

    const uint16_t* klds = &kv_lds[cur][0][0];
    const uint16_t* vlds = &kv_lds[cur][1][0];

    // ---- S^T = K Q^T ----
    f32x4 s[4];
#pragma unroll
    for (int tk = 0; tk < 4; ++tk) {
      const uint16_t* kr = klds + (tk * 16 + lm) * 64;
      bf16x8 ka0 = *(const bf16x8*)(kr + ((lg ^ sw) * 8));
      bf16x8 ka1 = *(const bf16x8*)(kr + (((lg + 4) ^ sw) * 8));
      f32x4 z4 = {0.f, 0.f, 0.f, 0.f};
      z4    = __builtin_amdgcn_mfma_f32_16x16x32_bf16(ka0, qa0, z4, 0, 0, 0);
      s[tk] = __builtin_amdgcn_mfma_f32_16x16x32_bf16(ka1, qa1, z4, 0, 0, 0);
    }

    // ---- online softmax: in-lane over 16 kv + 2 shuffles across lg groups ----
    f32x4 mx4 = s[0];
#pragma unroll
    for (int tk = 1; tk < 4; ++tk)
#pragma unroll
      for (int r = 0; r < 4; ++r) mx4[r] = fmaxf(mx4[r], s[tk][r]);
    float pm = fmaxf(fmaxf(mx4[0], mx4[1]), fmaxf(mx4[2], mx4[3]));
    pm = fmaxf(pm, __shfl_xor(pm, 16, 64));
    pm = fmaxf(pm, __shfl_xor(pm, 32, 64));
    float mn = fmaxf(m, pm);
    float sc = __expf(m - mn);
    m = mn;
    float rs = 0.f;
#pragma unroll
    for (int tk = 0; tk < 4; ++tk)
#pragma unroll
      for (int r = 0; r < 4; ++r) { float e = __expf(s[tk][r] - mn); s[tk][r] = e; rs += e; }
    rs += __shfl_xor(rs, 16, 64);
    rs += __shfl_xor(rs, 32, 64);
    l = l * sc + rs;
#pragma unroll
    for (int td = 0; td < 4; ++td) o[td] *= sc;

    // ---- P -> LDS (packed b64 writes), targeted lgkm fence ----
#pragma unroll
    for (int tk = 0; tk < 4; ++tk) {
      uint32_t p0 = (uint32_t)f2bf(s[tk][0]) | ((uint32_t)f2bf(s[tk][1]) << 16);
      uint32_t p1 = (uint32_t)f2bf(s[tk][2]) | ((uint32_t)f2bf(s[tk][3]) << 16);
      *(uint2*)&plw[lm][16 * tk + 4 * lg] = (uint2){p0, p1};
    }
    asm volatile("s_waitcnt lgkmcnt(0)" ::: "memory");
    __builtin_amdgcn_sched_barrier(0);
    bf16x8 pb0 = *(const bf16x8*)&plw[lm][8 * lg];
    bf16x8 pb1 = *(const bf16x8*)&plw[lm][32 + 8 * lg];

    // ---- O^T += V^T P^T ----
#pragma unroll
    for (int td = 0; td < 4; ++td) {
      const uint16_t* vr = vlds + (td * 16 + lm) * 64;
      bf16x8 va0 = *(const bf16x8*)(vr + ((lg ^ sw) * 8));
      bf16x8 va1 = *(const bf16x8*)(vr + (((lg + 4) ^ sw) * 8));
      o[td] = __builtin_amdgcn_mfma_f32_16x16x32_bf16(va0, pb0, o[td], 0, 0, 0);
      o[td] = __builtin_amdgcn_mfma_f32_16x16x32_bf16(va1, pb1, o[td], 0, 0, 0);
    }

    __syncthreads();   // drains this iter's prefetch (overlapped) + joins waves
    cur ^= 1;
  }

  // ---- write partials (unnormalized O, m, l) ----
  const int g = (b * 64 + qt) * 4 + wave;
  if (lg == 0) {
    mpart[((size_t)g * SPLIT + z) * 16 + lm] = m;
    lpart[((size_t)g * SPLIT + z) * 16 + lm] = l;
  }
  float* op = opart + ((size_t)g * SPLIT + z) * 1024 + (size_t)lm * 64;
#pragma unroll
  for (int td = 0; td < 4; ++td)
    *(f32x4*)(op + td * 16 + lg * 4) = o[td];
}

// ---------------- combine partials + fused epilogue ----------------
// grid (NN/64, BATCH), block 256 = 4 waves x 16 q-rows.
__global__ __launch_bounds__(256) void combine_kernel(
    const float* __restrict__ mpart, const float* __restrict__ lpart,
    const float* __restrict__ opart, const uint16_t* __restrict__ Wvb,
    const float* __restrict__ bv, const float* __restrict__ x,
    const float* __restrict__ sigma, float* __restrict__ out) {
  const int qt = blockIdx.x;
  const int b  = blockIdx.y;
  const int t    = threadIdx.x;
  const int wave = t >> 6;
  const int lane = t & 63;
  const int lg   = lane >> 4;
  const int lm   = lane & 15;

  __shared__ uint16_t plds[4][16][72];
  uint16_t (*plw)[72] = plds[wave];
  const int g = (b * 64 + qt) * 4 + wave;

  float m0 = mpart[((size_t)g * SPLIT + 0) * 16 + lm];
  float m1 = mpart[((size_t)g * SPLIT + 1) * 16 + lm];
  float l0 = lpart[((size_t)g * SPLIT + 0) * 16 + lm];
  float l1 = lpart[((size_t)g * SPLIT + 1) * 16 + lm];
  float M  = fmaxf(m0, m1);
  float e0 = __expf(m0 - M), e1 = __expf(m1 - M);
  float invL = 1.0f / (l0 * e0 + l1 * e1);
  float s0 = e0 * invL, s1 = e1 * invL;

  const float* o0 = opart + ((size_t)g * SPLIT + 0) * 1024 + (size_t)lm * 64;
  const float* o1 = opart + ((size_t)g * SPLIT + 1) * 1024 + (size_t)lm * 64;
#pragma unroll
  for (int k = 0; k < 4; ++k) {
    int d0 = lg * 16 + k * 4;
    f32x4 a0 = *(const f32x4*)(o0 + d0);
    f32x4 a1 = *(const f32x4*)(o1 + d0);
    uint32_t w0 = (uint32_t)f2bf(a0[0] * s0 + a1[0] * s1) |
                  ((uint32_t)f2bf(a0[1] * s0 + a1[1] * s1) << 16);
    uint32_t w1 = (uint32_t)f2bf(a0[2] * s0 + a1[2] * s1) |
                  ((uint32_t)f2bf(a0[3] * s0 + a1[3] * s1) << 16);
    *(uint2*)&plw[lm][d0] = (uint2){w0, w1};
  }
  asm volatile("s_waitcnt lgkmcnt(0)" ::: "memory");
  __builtin_amdgcn_sched_barrier(0);
  bf16x8 oa0 = *(const bf16x8*)&plw[lm][8 * lg];
  bf16x8 oa1 = *(const bf16x8*)&plw[lm][32 + 8 * lg];

  const float sg = sigma[0];
  const float* xb = x   + (size_t)b * CC * NN;
  float*       ob = out + (size_t)b * CC * NN;
  const int q0 = qt * 64 + wave * 16;
  const int qr = q0 + lg * 4;

#pragma unroll 4
  for (int tc2 = 0; tc2 < 32; ++tc2) {
    const int c = tc2 * 16 + lm;
    const uint16_t* Wp = Wvb + (size_t)c * DD + lg * 8;
    bf16x8 wb0 = *(const bf16x8*)Wp;
    bf16x8 wb1 = *(const bf16x8*)(Wp + 32);
    f32x4 a = {0.f, 0.f, 0.f, 0.f};
    a = __builtin_amdgcn_mfma_f32_16x16x32_bf16(oa0, wb0, a, 0, 0, 0);
    a = __builtin_amdgcn_mfma_f32_16x16x32_bf16(oa1, wb1, a, 0, 0, 0);
    const float bvc = bv[c];
    size_t base = (size_t)c * NN + qr;
    f32x4 xv = *(const f32x4*)(xb + base);
    f32x4 ov;
#pragma unroll
    for (int r = 0; r < 4; ++r) ov[r] = xv[r] + sg * (a[r] + bvc);
    *(f32x4*)(ob + base) = ov;
  }
}

extern "C" void kernel_launch(void* const* d_in, const int* in_sizes, int n_in,
                              void* d_out, int out_size, void* d_ws, size_t ws_size,
                              hipStream_t stream) {
  const float* x   = (const float*)d_in[0];
  const float* Wf  = (const float*)d_in[1];
  const float* bfp = (const float*)d_in[2];
  const float* Wg  = (const float*)d_in[3];
  const float* bgp = (const float*)d_in[4];
  const float* Wh  = (const float*)d_in[5];
  const float* bhp = (const float*)d_in[6];
  const float* Wv  = (const float*)d_in[7];
  const float* bv  = (const float*)d_in[8];
  const float* sg  = (const float*)d_in[9];
  float* out = (float*)d_out;

  const size_t nqk = (size_t)BATCH * NN * DD;        // 2M elems
  uint16_t* Qb  = (uint16_t*)d_ws;
  uint16_t* Kb  = Qb + nqk;
  uint16_t* Vt  = Kb + nqk;
  uint16_t* Wvb = Vt + nqk;
  float* mpart = (float*)(Wvb + (size_t)CC * DD);    // 2048*SPLIT*16 floats
  float* lpart = mpart + (size_t)2048 * SPLIT * 16;
  float* opart = lpart + (size_t)2048 * SPLIT * 16;  // 2048*SPLIT*1024 floats (16 MB)

  hipLaunchKernelGGL(cvt_wv_kernel, dim3(CC * DD / 256), dim3(256), 0, stream, Wv, Wvb);
  hipLaunchKernelGGL(proj_kernel, dim3(NN / 64, BATCH, 3), dim3(256), 0, stream,
                     x, Wf, bfp, Wg, bgp, Wh, bhp, Qb, Kb, Vt);
  hipLaunchKernelGGL(flash_kernel, dim3(NN / 64, BATCH, SPLIT), dim3(256), 0, stream,
                     Qb, Kb, Vt, mpart, lpart, opart);
  hipLaunchKernelGGL(combine_kernel, dim3(NN / 64, BATCH), dim3(256), 0, stream,
                     mpart, lpart, opart, Wvb, bv, x, sg, out);
}

// Round 3
// 144.619 us; speedup vs baseline: 2.4140x; 1.4928x over previous
//
#include <hip/hip_runtime.h>
#include <hip/hip_bf16.h>
#include <stdint.h>

#define BATCH 8
#define NN 4096
#define DD 64
#define CC 512
#define SPLIT 2
#define NT (NN / SPLIT / 64)   // 32 kv-tiles per split

using f32x4   = __attribute__((ext_vector_type(4))) float;
using f32x16  = __attribute__((ext_vector_type(16))) float;
using bf16x8  = __attribute__((ext_vector_type(8))) short;

__device__ __forceinline__ uint16_t f2bf(float f) {
  union { float f; uint32_t u; } v; v.f = f;
  uint32_t r = v.u + 0x7fffu + ((v.u >> 16) & 1u);
  return (uint16_t)(r >> 16);
}
__device__ __forceinline__ float bf2f(uint16_t h) {
  union { uint32_t u; float f; } v; v.u = ((uint32_t)h) << 16;
  return v.f;
}

__device__ __forceinline__ void gload16(const void* g, void* l) {
  __builtin_amdgcn_global_load_lds((const __attribute__((address_space(1))) void*)g,
                                   (__attribute__((address_space(3))) void*)l, 16, 0, 0);
}

// ---------------- weights -> bf16 ----------------
// Wb[p][ch][c] with 16B-chunk swizzle: chunk s (=(c>>3)&7) of row ch stored at slot s^(ch&7)
// within each 64-c K-step. Wvb plain [c][d].
__global__ void cvt_w_kernel(const float* __restrict__ Wf, const float* __restrict__ Wg,
                             const float* __restrict__ Wh, const float* __restrict__ Wv,
                             uint16_t* __restrict__ Wb, uint16_t* __restrict__ Wvb) {
  int i = blockIdx.x * 256 + threadIdx.x;
  if (i < 3 * 64 * 512) {
    int p = i >> 15, r = i & 32767, ch = r >> 9, c = r & 511;
    const float* W = (p == 0) ? Wf : (p == 1) ? Wg : Wh;
    int slot = ((c >> 3) & 7) ^ (ch & 7);
    Wb[(size_t)(p * 64 + ch) * 512 + (c >> 6) * 64 + slot * 8 + (c & 7)] = f2bf(W[ch * 512 + c]);
  } else if (i < 3 * 64 * 512 + 512 * 64) {
    int j = i - 3 * 64 * 512;
    Wvb[j] = f2bf(Wv[j]);
  }
}

// ---------------- fused projections ff/fg/fh via MFMA ----------------
// grid 512 (b*64+nt), block 256 = 4 waves.  Per block: 64 n x 64 ch x 3 proj.
// Wave w: n-half = (w&1)*32, ch-half = (w>>1)*32, all 3 projections.
__global__ __launch_bounds__(256) void proj_kernel(
    const float* __restrict__ x, const uint16_t* __restrict__ Wb,
    const float* __restrict__ bfp, const float* __restrict__ bgp, const float* __restrict__ bhp,
    uint16_t* __restrict__ Qb, uint16_t* __restrict__ Kb, uint16_t* __restrict__ Vt) {
  const int bid = blockIdx.x;
  const int b = bid >> 6, nt = bid & 63, n0 = nt * 64;
  const int t = threadIdx.x, w = t >> 6, lane = t & 63;
  const int l5 = lane >> 5, lm = lane & 31;

  __shared__ uint16_t xl[2][64 * 64];    // row n (64 elem): chunk s at slot s^(n&7)
  __shared__ uint16_t wl[2][192 * 64];   // row p*64+ch: chunks pre-swizzled in global layout

  const float* xp = x + (size_t)b * CC * NN + n0;
  const int nB0 = (w & 1) * 32, ch0w = (w >> 1) * 32;

  f32x16 acc[3];
#pragma unroll
  for (int p = 0; p < 3; ++p)
#pragma unroll
    for (int q = 0; q < 16; ++q) acc[p][q] = 0.f;

  float xr[16];

  auto stageW = [&](int buf, int k) {
#pragma unroll
    for (int i = 0; i < 6; ++i) {
      int e = t + i * 256;                       // e>>3 = row, e&7 = stored chunk
      const uint16_t* src = Wb + (size_t)(e >> 3) * 512 + k * 64 + (e & 7) * 8;
      gload16(src, &wl[buf][(size_t)(w * 64 + i * 256) * 8]);
    }
  };
  auto loadX = [&](int k) {
#pragma unroll
    for (int r = 0; r < 2; ++r)
#pragma unroll
      for (int j = 0; j < 8; ++j)
        xr[r * 8 + j] = xp[(size_t)(k * 64 + r * 32 + w * 8 + j) * NN + lane];
  };
  auto writeX = [&](int buf) {
#pragma unroll
    for (int r = 0; r < 2; ++r) {
      int slot = (r * 4 + w) ^ (lane & 7);
      uint4 v;
      v.x = (uint32_t)f2bf(xr[r * 8 + 0]) | ((uint32_t)f2bf(xr[r * 8 + 1]) << 16);
      v.y = (uint32_t)f2bf(xr[r * 8 + 2]) | ((uint32_t)f2bf(xr[r * 8 + 3]) << 16);
      v.z = (uint32_t)f2bf(xr[r * 8 + 4]) | ((uint32_t)f2bf(xr[r * 8 + 5]) << 16);
      v.w = (uint32_t)f2bf(xr[r * 8 + 6]) | ((uint32_t)f2bf(xr[r * 8 + 7]) << 16);
      *(uint4*)&xl[buf][lane * 64 + slot * 8] = v;
    }
  };

  stageW(0, 0);
  loadX(0);
  writeX(0);
  __syncthreads();

  for (int k = 0; k < 8; ++k) {
    const int buf = k & 1;
    if (k < 7) { loadX(k + 1); stageW(buf ^ 1, k + 1); }
#pragma unroll
    for (int ks = 0; ks < 4; ++ks) {
      const int slot = (ks * 2 + l5) ^ (lm & 7);
      bf16x8 bfrag = *(const bf16x8*)&xl[buf][(nB0 + lm) * 64 + slot * 8];
#pragma unroll
      for (int p = 0; p < 3; ++p) {
        bf16x8 afrag = *(const bf16x8*)&wl[buf][(size_t)(p * 64 + ch0w + lm) * 64 + slot * 8];
        acc[p] = __builtin_amdgcn_mfma_f32_32x32x16_bf16(afrag, bfrag, acc[p], 0, 0, 0);
      }
    }
    if (k < 7) writeX(buf ^ 1);
    __syncthreads();
  }

  // epilogue: D[ch = ch0w + (q&3)+8*(q>>2)+4*l5][n = n0+nB0+lm]
  const int nG = n0 + nB0 + lm;
  const float* biasP[3] = {bfp, bgp, bhp};
#pragma unroll
  for (int p = 0; p < 2; ++p) {
    uint16_t* dst = (p == 0 ? Qb : Kb) + ((size_t)b * NN + nG) * DD;
#pragma unroll
    for (int g = 0; g < 4; ++g) {
      const int chb = ch0w + 4 * l5 + 8 * g;
      uint2 v;
      v.x = (uint32_t)f2bf(acc[p][g * 4 + 0] + biasP[p][chb + 0]) |
            ((uint32_t)f2bf(acc[p][g * 4 + 1] + biasP[p][chb + 1]) << 16);
      v.y = (uint32_t)f2bf(acc[p][g * 4 + 2] + biasP[p][chb + 2]) |
            ((uint32_t)f2bf(acc[p][g * 4 + 3] + biasP[p][chb + 3]) << 16);
      *(uint2*)&dst[chb] = v;
    }
  }
  {
    uint16_t* dst = Vt + (size_t)b * DD * NN + nG;
#pragma unroll
    for (int q = 0; q < 16; ++q) {
      const int d = ch0w + 4 * l5 + 8 * (q >> 2) + (q & 3);
      dst[(size_t)d * NN] = f2bf(acc[2][q] + bhp[d]);
    }
  }
}

// ---------------- flash attention partial (split-KV) ----------------
// 1D grid 1024, XCD-swizzled so XCD x owns batch x (K/V L2-resident).
__global__ __launch_bounds__(256) void flash_kernel(
    const uint16_t* __restrict__ Qb, const uint16_t* __restrict__ Kb,
    const uint16_t* __restrict__ Vt,
    float* __restrict__ mpart, float* __restrict__ lpart, uint16_t* __restrict__ opart) {
  const int bid = blockIdx.x;
  const int wid = (bid & 7) * 128 + (bid >> 3);
  const int qt = wid & 63;
  const int bz = wid >> 6;      // 0..15
  const int b  = bz >> 1;
  const int z  = bz & 1;
  const int t    = threadIdx.x;
  const int wave = t >> 6;
  const int lane = t & 63;
  const int lg   = lane >> 4;
  const int lm   = lane & 15;

  __shared__ uint16_t kv_lds[2][2][64 * 64];
  __shared__ uint16_t plds[4][16][72];
  uint16_t (*plw)[72] = plds[wave];

  const int q0 = qt * 64 + wave * 16;
  const uint16_t* Qp = Qb + ((size_t)b * NN + q0 + lm) * DD + lg * 8;
  bf16x8 qa0 = *(const bf16x8*)Qp;
  bf16x8 qa1 = *(const bf16x8*)(Qp + 32);

  const uint16_t* Kbase = Kb + (size_t)b * NN * DD;
  const uint16_t* Vbase = Vt + (size_t)b * DD * NN;
  const int kvstart = z * (NN / SPLIT);

  const int srow = wave * 16 + (lane >> 3);
  const int csw  = (lane & 7) ^ ((lane >> 3) & 7);

  auto stage = [&](int buf, int kv0) {
    uint16_t* kl = &kv_lds[buf][0][0] + wave * 1024;
    uint16_t* vl = &kv_lds[buf][1][0] + wave * 1024;
    gload16(Kbase + ((size_t)kv0 + srow) * DD + csw * 8,       kl);
    gload16(Kbase + ((size_t)kv0 + srow + 8) * DD + csw * 8,   kl + 512);
    gload16(Vbase + (size_t)srow * NN + kv0 + csw * 8,         vl);
    gload16(Vbase + (size_t)(srow + 8) * NN + kv0 + csw * 8,   vl + 512);
  };

  f32x4 o[4] = {};
  float m = -1e30f, l = 0.f;

  stage(0, kvstart);
  __syncthreads();

  int cur = 0;
  const int sw = lm & 7;
  for (int it = 0; it < NT; ++it) {
    const int kv0 = kvstart + it * 64;
    if (it + 1 < NT) stage(cur ^ 1, kv0 + 64);

    const uint16_t* klds = &kv_lds[cur][0][0];
    const uint16_t* vlds = &kv_lds[cur][1][0];

    f32x4 s[4];
#pragma unroll
    for (int tk = 0; tk < 4; ++tk) {
      const uint16_t* kr = klds + (tk * 16 + lm) * 64;
      bf16x8 ka0 = *(const bf16x8*)(kr + ((lg ^ sw) * 8));
      bf16x8 ka1 = *(const bf16x8*)(kr + (((lg + 4) ^ sw) * 8));
      f32x4 z4 = {0.f, 0.f, 0.f, 0.f};
      z4    = __builtin_amdgcn_mfma_f32_16x16x32_bf16(ka0, qa0, z4, 0, 0, 0);
      s[tk] = __builtin_amdgcn_mfma_f32_16x16x32_bf16(ka1, qa1, z4, 0, 0, 0);
    }

    f32x4 mx4 = s[0];
#pragma unroll
    for (int tk = 1; tk < 4; ++tk)
#pragma unroll
      for (int r = 0; r < 4; ++r) mx4[r] = fmaxf(mx4[r], s[tk][r]);
    float pm = fmaxf(fmaxf(mx4[0], mx4[1]), fmaxf(mx4[2], mx4[3]));
    pm = fmaxf(pm, __shfl_xor(pm, 16, 64));
    pm = fmaxf(pm, __shfl_xor(pm, 32, 64));
    float mn = fmaxf(m, pm);
    float sc = __expf(m - mn);
    m = mn;
    float rs = 0.f;
#pragma unroll
    for (int tk = 0; tk < 4; ++tk)
#pragma unroll
      for (int r = 0; r < 4; ++r) { float e = __expf(s[tk][r] - mn); s[tk][r] = e; rs += e; }
    rs += __shfl_xor(rs, 16, 64);
    rs += __shfl_xor(rs, 32, 64);
    l = l * sc + rs;
#pragma unroll
    for (int td = 0; td < 4; ++td) o[td] *= sc;

#pragma unroll
    for (int tk = 0; tk < 4; ++tk) {
      uint32_t p0 = (uint32_t)f2bf(s[tk][0]) | ((uint32_t)f2bf(s[tk][1]) << 16);
      uint32_t p1 = (uint32_t)f2bf(s[tk][2]) | ((uint32_t)f2bf(s[tk][3]) << 16);
      *(uint2*)&plw[lm][16 * tk + 4 * lg] = (uint2){p0, p1};
    }
    asm volatile("s_waitcnt lgkmcnt(0)" ::: "memory");
    __builtin_amdgcn_sched_barrier(0);
    bf16x8 pb0 = *(const bf16x8*)&plw[lm][8 * lg];
    bf16x8 pb1 = *(const bf16x8*)&plw[lm][32 + 8 * lg];

#pragma unroll
    for (int td = 0; td < 4; ++td) {
      const uint16_t* vr = vlds + (td * 16 + lm) * 64;
      bf16x8 va0 = *(const bf16x8*)(vr + ((lg ^ sw) * 8));
      bf16x8 va1 = *(const bf16x8*)(vr + (((lg + 4) ^ sw) * 8));
      o[td] = __builtin_amdgcn_mfma_f32_16x16x32_bf16(va0, pb0, o[td], 0, 0, 0);
      o[td] = __builtin_amdgcn_mfma_f32_16x16x32_bf16(va1, pb1, o[td], 0, 0, 0);
    }

    __syncthreads();
    cur ^= 1;
  }

  const int g = (b * 64 + qt) * 4 + wave;
  if (lg == 0) {
    mpart[((size_t)g * SPLIT + z) * 16 + lm] = m;
    lpart[((size_t)g * SPLIT + z) * 16 + lm] = l;
  }
  const float invl = 1.0f / l;
  uint16_t* op = opart + ((size_t)g * SPLIT + z) * 1024 + (size_t)lm * 64;
#pragma unroll
  for (int td = 0; td < 4; ++td) {
    uint2 v;
    v.x = (uint32_t)f2bf(o[td][0] * invl) | ((uint32_t)f2bf(o[td][1] * invl) << 16);
    v.y = (uint32_t)f2bf(o[td][2] * invl) | ((uint32_t)f2bf(o[td][3] * invl) << 16);
    *(uint2*)&op[td * 16 + lg * 4] = v;
  }
}

// ---------------- combine partials + fused epilogue ----------------
__global__ __launch_bounds__(256) void combine_kernel(
    const float* __restrict__ mpart, const float* __restrict__ lpart,
    const uint16_t* __restrict__ opart, const uint16_t* __restrict__ Wvb,
    const float* __restrict__ bv, const float* __restrict__ x,
    const float* __restrict__ sigma, float* __restrict__ out) {
  const int qt = blockIdx.x;
  const int b  = blockIdx.y;
  const int t    = threadIdx.x;
  const int wave = t >> 6;
  const int lane = t & 63;
  const int lg   = lane >> 4;
  const int lm   = lane & 15;

  __shared__ uint16_t plds[4][16][72];
  uint16_t (*plw)[72] = plds[wave];
  const int g = (b * 64 + qt) * 4 + wave;

  float m0 = mpart[((size_t)g * SPLIT + 0) * 16 + lm];
  float m1 = mpart[((size_t)g * SPLIT + 1) * 16 + lm];
  float l0 = lpart[((size_t)g * SPLIT + 0) * 16 + lm];
  float l1 = lpart[((size_t)g * SPLIT + 1) * 16 + lm];
  float M  = fmaxf(m0, m1);
  float e0 = l0 * __expf(m0 - M), e1 = l1 * __expf(m1 - M);
  float inv = 1.0f / (e0 + e1);
  float a0w = e0 * inv, a1w = e1 * inv;

  const uint16_t* o0 = opart + ((size_t)g * SPLIT + 0) * 1024 + (size_t)lm * 64;
  const uint16_t* o1 = opart + ((size_t)g * SPLIT + 1) * 1024 + (size_t)lm * 64;
#pragma unroll
  for (int k = 0; k < 4; ++k) {
    int d0 = lg * 16 + k * 4;
    uint2 r0 = *(const uint2*)&o0[d0];
    uint2 r1 = *(const uint2*)&o1[d0];
    float v0 = bf2f(r0.x & 0xffff) * a0w + bf2f(r1.x & 0xffff) * a1w;
    float v1 = bf2f(r0.x >> 16)    * a0w + bf2f(r1.x >> 16)    * a1w;
    float v2 = bf2f(r0.y & 0xffff) * a0w + bf2f(r1.y & 0xffff) * a1w;
    float v3 = bf2f(r0.y >> 16)    * a0w + bf2f(r1.y >> 16)    * a1w;
    uint2 wv;
    wv.x = (uint32_t)f2bf(v0) | ((uint32_t)f2bf(v1) << 16);
    wv.y = (uint32_t)f2bf(v2) | ((uint32_t)f2bf(v3) << 16);
    *(uint2*)&plw[lm][d0] = wv;
  }
  asm volatile("s_waitcnt lgkmcnt(0)" ::: "memory");
  __builtin_amdgcn_sched_barrier(0);
  bf16x8 oa0 = *(const bf16x8*)&plw[lm][8 * lg];
  bf16x8 oa1 = *(const bf16x8*)&plw[lm][32 + 8 * lg];

  const float sg = sigma[0];
  const float* xb = x   + (size_t)b * CC * NN;
  float*       ob = out + (size_t)b * CC * NN;
  const int q0 = qt * 64 + wave * 16;
  const int qr = q0 + lg * 4;

#pragma unroll 4
  for (int tc2 = 0; tc2 < 32; ++tc2) {
    const int c = tc2 * 16 + lm;
    const uint16_t* Wp = Wvb + (size_t)c * DD + lg * 8;
    bf16x8 wb0 = *(const bf16x8*)Wp;
    bf16x8 wb1 = *(const bf16x8*)(Wp + 32);
    f32x4 a = {0.f, 0.f, 0.f, 0.f};
    a = __builtin_amdgcn_mfma_f32_16x16x32_bf16(oa0, wb0, a, 0, 0, 0);
    a = __builtin_amdgcn_mfma_f32_16x16x32_bf16(oa1, wb1, a, 0, 0, 0);
    const float bvc = bv[c];
    size_t base = (size_t)c * NN + qr;
    f32x4 xv = *(const f32x4*)(xb + base);
    f32x4 ov;
#pragma unroll
    for (int r = 0; r < 4; ++r) ov[r] = xv[r] + sg * (a[r] + bvc);
    *(f32x4*)(ob + base) = ov;
  }
}

extern "C" void kernel_launch(void* const* d_in, const int* in_sizes, int n_in,
                              void* d_out, int out_size, void* d_ws, size_t ws_size,
                              hipStream_t stream) {
  const float* x   = (const float*)d_in[0];
  const float* Wf  = (const float*)d_in[1];
  const float* bfp = (const float*)d_in[2];
  const float* Wg  = (const float*)d_in[3];
  const float* bgp = (const float*)d_in[4];
  const float* Wh  = (const float*)d_in[5];
  const float* bhp = (const float*)d_in[6];
  const float* Wv  = (const float*)d_in[7];
  const float* bv  = (const float*)d_in[8];
  const float* sg  = (const float*)d_in[9];
  float* out = (float*)d_out;

  const size_t nqk = (size_t)BATCH * NN * DD;
  uint16_t* Qb   = (uint16_t*)d_ws;
  uint16_t* Kb   = Qb + nqk;
  uint16_t* Vt   = Kb + nqk;
  uint16_t* Wvb  = Vt + nqk;
  uint16_t* Wb   = Wvb + (size_t)CC * DD;
  float* mpart   = (float*)(Wb + (size_t)3 * 64 * 512);
  float* lpart   = mpart + (size_t)2048 * SPLIT * 16;
  uint16_t* opart = (uint16_t*)(lpart + (size_t)2048 * SPLIT * 16);

  hipLaunchKernelGGL(cvt_w_kernel, dim3(512), dim3(256), 0, stream, Wf, Wg, Wh, Wv, Wb, Wvb);
  hipLaunchKernelGGL(proj_kernel, dim3(512), dim3(256), 0, stream,
                     x, Wb, bfp, bgp, bhp, Qb, Kb, Vt);
  hipLaunchKernelGGL(flash_kernel, dim3(1024), dim3(256), 0, stream,
                     Qb, Kb, Vt, mpart, lpart, opart);
  hipLaunchKernelGGL(combine_kernel, dim3(NN / 64, BATCH), dim3(256), 0, stream,
                     mpart, lpart, opart, Wvb, bv, x, sg, out);
}